// Round 9
// baseline (14937.126 us; speedup 1.0000x reference)
//
#include <hip/hip_runtime.h>
#include <math.h>

#define DM   1024
#define BSZ  4
#define LSEQ 4096
#define GPB  32            // WGs per batch group (1 per CU, co-resident on one XCD)
#define RPW  32            // rows per WG (DM / GPB)
#define TPB  1024
#define SEGC 32            // columns per thread segment
#define SSP  68            // padded words per 64-col block
#define HSW2 1088          // 16 * SSP staged words per buffer

typedef unsigned long long u64;

// ---------------- Phase 1: bx = x @ B_w^T (fp32 NT GEMM) ----------------
__global__ __launch_bounds__(256) void bx_gemm_kernel(
    const float* __restrict__ X, const float* __restrict__ Bw,
    float* __restrict__ out)
{
    __shared__ float xs[16][68];
    __shared__ float bs[16][68];
    const int bm = blockIdx.x, bn = blockIdx.y;
    const int t  = threadIdx.x;
    const int tx = t & 15, ty = t >> 4;
    const int ml = t >> 2;
    const int kq = (t & 3) * 4;
    const float* xg = X  + (size_t)(bm * 64 + ml) * DM + kq;
    const float* bg = Bw + (size_t)(bn * 64 + ml) * DM + kq;
    float acc[4][4] = {};
    for (int k0 = 0; k0 < DM; k0 += 16) {
        float4 xv = *(const float4*)(xg + k0);
        float4 bv = *(const float4*)(bg + k0);
        __syncthreads();
        xs[kq+0][ml] = xv.x; xs[kq+1][ml] = xv.y; xs[kq+2][ml] = xv.z; xs[kq+3][ml] = xv.w;
        bs[kq+0][ml] = bv.x; bs[kq+1][ml] = bv.y; bs[kq+2][ml] = bv.z; bs[kq+3][ml] = bv.w;
        __syncthreads();
        #pragma unroll
        for (int kk = 0; kk < 16; ++kk) {
            float a[4], c[4];
            #pragma unroll
            for (int i = 0; i < 4; ++i) a[i] = xs[kk][ty*4+i];
            #pragma unroll
            for (int j = 0; j < 4; ++j) c[j] = bs[kk][tx*4+j];
            #pragma unroll
            for (int i = 0; i < 4; ++i)
                #pragma unroll
                for (int j = 0; j < 4; ++j)
                    acc[i][j] += a[i] * c[j];
        }
    }
    #pragma unroll
    for (int i = 0; i < 4; ++i) {
        float4 v = make_float4(acc[i][0], acc[i][1], acc[i][2], acc[i][3]);
        *(float4*)(out + (size_t)(bm*64 + ty*4 + i)*DM + bn*64 + tx*4) = v;
    }
}

__device__ __forceinline__ unsigned tg(u64 v) { return (unsigned)(v >> 32); }

// XCD-L2 coherent read: sc0 bypasses L1, stays within this XCD's L2.
// Fused wait (spin/deferred use only).
__device__ __forceinline__ u64 l2_load(const u64* p)
{
    u64 v;
    asm volatile("global_load_dwordx2 %0, %1, off sc0\n\t"
                 "s_waitcnt vmcnt(0)"
                 : "=v"(v) : "v"(p) : "memory");
    return v;
}

// fast tanh: (e^{2x}-1)/(e^{2x}+1); correct saturation via exp overflow
__device__ __forceinline__ float fast_tanh(float x)
{
    float e = __expf(2.0f * x);
    return (e - 1.0f) / (e + 1.0f);
}

// ---------------- Phase 2: fused scan, XCD-local tagged exchange ----------
// 256 WGs launched; r=blockIdx&7: r<4 -> batch group r (32 WGs, 1/CU, on XCD
// r under round-robin dispatch), r>=4 -> exit. 1024 threads: row = t>>5
// (0..31), seg = t&31 (32 cols). A,C row-slices in regs (32 floats each).
// Each thread polls ONE tagged word (col t). State = (tag<<32|float) u64,
// dual copy: fast (plain store + sc0 asm load -> XCD L2) and safe (agent
// atomics -> MALL; k=0 prologue + placement-failure fallback w/ latch).
// Raw lgkmcnt barrier (LDS staging is the only cross-thread hazard) -- no
// vmcnt drain of y-stores/prefetches. Spec load for k+1 issued at iteration
// END (closest to producers' stores). hs double-buffered, 1 barrier/step.
__global__ __launch_bounds__(TPB, 4) void scan_kernel(
    const float* __restrict__ A, const float* __restrict__ Cw,
    const float* __restrict__ Dv, const float* __restrict__ X,
    float* __restrict__ Y, u64* hfast, u64* hsafe)
{
    const int r = blockIdx.x & 7;
    if (r >= BSZ) return;
    const int b  = r;
    const int gw = blockIdx.x >> 3;          // 0..31
    const int r0 = gw * RPW;

    __shared__ float hs0[2 * HSW2];
    const int t   = threadIdx.x;
    const int row = t >> 5;                  // 0..31
    const int seg = t & 31;                  // 32-col segment
    const bool lead = (seg == 0);

    // A and C row-slices -> registers (32 floats each)
    float ra[SEGC], rc[SEGC];
    {
        const float* Ap = A  + (size_t)(r0 + row) * DM + seg * SEGC;
        const float* Cp = Cw + (size_t)(r0 + row) * DM + seg * SEGC;
        #pragma unroll
        for (int u = 0; u < SEGC / 4; ++u) {
            float4 v = *(const float4*)(Ap + u*4);
            ra[u*4+0]=v.x; ra[u*4+1]=v.y; ra[u*4+2]=v.z; ra[u*4+3]=v.w;
            float4 w = *(const float4*)(Cp + u*4);
            rc[u*4+0]=w.x; rc[u*4+1]=w.y; rc[u*4+2]=w.z; rc[u*4+3]=w.w;
        }
    }
    const float dv = Dv[r0 + row];

    const int c0 = t;
    const int s0 = (t >> 6) * SSP + (t & 63);          // staging slot
    const int hb = (seg >> 1) * SSP + (seg & 1) * 32;  // matvec read base
    int fastok = 1;

    // prologue spec for k=0: SAFE copy only (freshly memset through MALL)
    u64 v0 = __hip_atomic_load(hsafe + (size_t)b * DM + c0, __ATOMIC_RELAXED,
                               __HIP_MEMORY_SCOPE_AGENT);
    float bxv = 0.f;          // bx_k    (tanh input at iteration k)
    float xv  = 0.f;          // x_{k-1} (y-store at iteration k)
    if (lead) bxv = Y[(size_t)b*LSEQ*DM + r0 + row];

    for (int k = 0; k <= LSEQ; ++k) {
        const unsigned tag = (unsigned)k;
        const size_t slot = (size_t)(k & 1) * BSZ * DM + (size_t)b * DM;

        // ---- finish poll for s_k (spec load issued last iteration) ----
        if (tg(v0) != tag) {
            if (k == 0 || !fastok) {
                int spins = 0;
                do {
                    v0 = __hip_atomic_load(hsafe + slot + c0, __ATOMIC_RELAXED,
                                           __HIP_MEMORY_SCOPE_AGENT);
                } while (tg(v0) != tag && ++spins < (1 << 20));
            } else {
                int i = 0;
                while (tg(v0) != tag && i < 64) { v0 = l2_load(hfast + slot + c0); ++i; }
                if (tg(v0) != tag) {
                    int spins = 0;
                    do {
                        v0 = __hip_atomic_load(hsafe + slot + c0, __ATOMIC_RELAXED,
                                               __HIP_MEMORY_SCOPE_AGENT);
                    } while (tg(v0) != tag && ++spins < (1 << 20));
                    u64 f = l2_load(hfast + slot + c0);
                    if (tg(f) != tag) fastok = 0;   // placement failed: latch off
                }
            }
        }

        float* hsk = hs0 + (k & 1) * HSW2;
        hsk[s0] = __uint_as_float((unsigned)v0);
        // raw barrier: LDS staging is the only cross-thread hazard ->
        // drain lgkm only, NOT vmcnt (y-stores/prefetches stay in flight)
        asm volatile("s_waitcnt lgkmcnt(0)\n\ts_barrier" ::: "memory");

        // ---- fused A+C matvec: one pass over this thread's 32 cols ----
        float accA = 0.f, accC = 0.f;
        {
            const float4* h4p = (const float4*)(hsk + hb);
            #pragma unroll
            for (int u = 0; u < SEGC / 4; ++u) {
                float4 h4 = h4p[u];
                accA += ra[u*4+0]*h4.x + ra[u*4+1]*h4.y + ra[u*4+2]*h4.z + ra[u*4+3]*h4.w;
                accC += rc[u*4+0]*h4.x + rc[u*4+1]*h4.y + rc[u*4+2]*h4.z + rc[u*4+3]*h4.w;
            }
        }

        float xv_next = xv;
        const size_t nslot = (size_t)((k+1) & 1) * BSZ * DM + (size_t)b * DM;
        if (k < LSEQ) {
            // ---- critical path: reduce accA, tanh, dual h-store ----
            accA += __shfl_xor(accA, 1);
            accA += __shfl_xor(accA, 2);
            accA += __shfl_xor(accA, 4);
            accA += __shfl_xor(accA, 8);
            accA += __shfl_xor(accA, 16);
            if (lead) {
                float hv = fast_tanh(accA + bxv);
                u64 pk = ((u64)(unsigned)(k + 1) << 32) | (u64)__float_as_uint(hv);
                __hip_atomic_store(hfast + nslot + r0 + row, pk,
                                   __ATOMIC_RELAXED, __HIP_MEMORY_SCOPE_WORKGROUP);
                __hip_atomic_store(hsafe + nslot + r0 + row, pk,
                                   __ATOMIC_RELAXED, __HIP_MEMORY_SCOPE_AGENT);
            }
            // prefetch next-step operands (lead lanes only)
            if (lead) {
                xv_next = X[(size_t)b*LSEQ*DM + (size_t)k*DM + r0 + row];   // x_k
                if (k + 1 < LSEQ)
                    bxv = Y[(size_t)b*LSEQ*DM + (size_t)(k+1)*DM + r0 + row];
            }
        }

        // ---- deferred: reduce accC + y-store (overlaps exchange) ----
        if (k > 0) {
            accC += __shfl_xor(accC, 1);
            accC += __shfl_xor(accC, 2);
            accC += __shfl_xor(accC, 4);
            accC += __shfl_xor(accC, 8);
            accC += __shfl_xor(accC, 16);
            if (lead) {
                const size_t yoff = (size_t)b*LSEQ*DM + (size_t)(k-1)*DM + r0 + row;
                Y[yoff] = accC + dv * xv;        // y_{k-1} = C s_k + D x_{k-1}
            }
        }
        xv = xv_next;

        // ---- spec load for step k+1, issued LAST (max producer overlap) ----
        if (k < LSEQ) {
            if (fastok) v0 = l2_load(hfast + nslot + c0);
            else        v0 = __hip_atomic_load(hsafe + nslot + c0, __ATOMIC_RELAXED,
                                               __HIP_MEMORY_SCOPE_AGENT);
        }
    }
}

extern "C" void kernel_launch(void* const* d_in, const int* in_sizes, int n_in,
                              void* d_out, int out_size, void* d_ws, size_t ws_size,
                              hipStream_t stream)
{
    const float* X  = (const float*)d_in[0];
    const float* A  = (const float*)d_in[1];
    const float* Bw = (const float*)d_in[2];
    const float* Cw = (const float*)d_in[3];
    const float* Dv = (const float*)d_in[4];
    float* Y    = (float*)d_out;
    u64* hfast  = (u64*)d_ws;
    u64* hsafe  = hfast + (size_t)2 * BSZ * DM;

    // zero both tagged copies every launch: (0.0f, tag 0) == s_0 ready
    hipMemsetAsync(d_ws, 0, (size_t)4 * BSZ * DM * sizeof(u64), stream);

    dim3 g1((BSZ * LSEQ) / 64, DM / 64);
    bx_gemm_kernel<<<g1, 256, 0, stream>>>(X, Bw, Y);
    scan_kernel<<<256, TPB, 0, stream>>>(A, Cw, Dv, X, Y, hfast, hsafe);
}